// Round 8
// baseline (250.827 us; speedup 1.0000x reference)
//
#include <hip/hip_runtime.h>

#define NC   8
#define MTOT 17408   // NSPOKE*NVEC = 34*512

typedef __attribute__((ext_vector_type(8)))  short short8;
typedef __attribute__((ext_vector_type(16))) float f32x16;

typedef __attribute__((address_space(3))) unsigned       lds_uint;
typedef const __attribute__((address_space(1))) unsigned glb_uint;

static __device__ __forceinline__ short f2bf(float f) {
    union { float f; unsigned u; } v; v.f = f;
    return (short)((v.u + 0x7fffu + ((v.u >> 16) & 1u)) >> 16);
}

// Fused prep (R6-proven version, per-j sincos).
// Blocks [0,2048): src planes  src[c][a][b] = (X*C) -> Sr, Si.
// Blocks [2048,4224): Eb table in 32x32x16 B-fragment order:
//   Br[kt][ks] at EbT[(kt*32+ks)*512 + lane*8 + j], Bi at +8192 within kt blk:
//   exp(-i*t_k*b'), k = kt*32+(lane&31), b' = ks*16+(lane>>5)*8+j-128.
__global__ __launch_bounds__(256) void prep(
        const float* __restrict__ X, const float* __restrict__ C,
        const float* __restrict__ angles,
        short* __restrict__ Sr, short* __restrict__ Si,
        short* __restrict__ EbT) {
    int bx = blockIdx.x;
    if (bx < 2048) {
        int idx = bx * 256 + threadIdx.x;   // [0, 8*65536)
        int ab = idx & 65535;
        float xr = X[ab * 2 + 0], xi = X[ab * 2 + 1];
        float cr = C[idx * 2 + 0], ci = C[idx * 2 + 1];
        Sr[idx] = f2bf(xr * cr - xi * ci);
        Si[idx] = f2bf(xr * ci + xi * cr);
    } else {
        int gid  = (bx - 2048) * 256 + threadIdx.x;  // [0, 544*1024)
        int kt   = gid >> 10;
        int r    = gid & 1023;
        int ks   = r >> 6;
        int lane = r & 63;
        int k    = kt * 32 + (lane & 31);
        float t  = angles[k * 2 + 1];
        short8 re, im;
        #pragma unroll
        for (int j = 0; j < 8; ++j) {
            float xb = (float)(ks * 16 + (lane >> 5) * 8 + j - 128);
            float sn, cs;
            __sincosf(t * xb, &sn, &cs);
            re[j] = f2bf(cs);
            im[j] = f2bf(-sn);
        }
        short* base = EbT + (size_t)(kt * 32 + ks) * 512 + lane * 8;
        *(short8*)(base)        = re;
        *(short8*)(base + 8192) = im;
    }
}

// Main: y[c,k] = w[k] * sum_a Ea[k,a] * sum_b src[c,a,b] * Eb[k,b]
// 8 waves x 512 threads; wave w owns kt = ktg*8+w (32 k-cols).
// a-tile = 64 rows x 256 b x 2 planes = 64KB, DOUBLE buffered (128KB dyn LDS,
// 1 block/CU). B[ks] loaded once per at and reused across both 32-row
// subtiles (halves B-L2 traffic vs 32-row tiles). P[2][4] = 128 AGPRs.
// Proven dbuf barrier discipline: vmcnt(0)+s_barrier at tile top only;
// stage-issue spread across phases targeting the other buffer.
// Grid 576 = 72 ktg-slots x 8 coils, early-exit ktg>=68; XCD = ktg%8 so the
// 8 coil-blocks sharing an EbT slice co-reside per XCD (~4MB L2 set).
template<int USE_TABLE>
__global__ __launch_bounds__(512, 1) void nufft_fwd(
        const float* __restrict__ angles, const float* __restrict__ w,
        const short* __restrict__ SrP, const short* __restrict__ SiP,
        const short* __restrict__ EbT, float* __restrict__ out) {
    extern __shared__ char lds[];       // 131072 bytes

    const int tid  = threadIdx.x;
    const int lane = tid & 63;
    const int wv   = tid >> 6;              // 0..7
    const int bid  = blockIdx.x;            // 0..575
    const int ktg  = bid % 72;              // XCD = bid%8 = ktg%8 (72%8==0)
    const int c    = bid / 72;
    if (ktg >= 68) return;                   // padded grid tail

    const int col  = lane & 31;             // MFMA: A-row / B-col / D-col
    const int hi   = lane >> 5;             // MFMA: K-half selector
    const int kt   = ktg * 8 + wv;          // [0,544)
    const int k    = kt * 32 + col;
    const float s  = angles[k * 2 + 0];

    const short* Sr = SrP + c * 65536;
    const short* Si = SiP + c * 65536;
    const short* tb = EbT + (size_t)kt * 16384 + lane * 8;
    const float  t  = USE_TABLE ? 0.f : angles[k * 2 + 1];

    // Phasors p[r] = exp(-i*s*a0), a0 = r + 4*hi - 128; rotated by exp(-i*8s)
    // after each quad (8 quads/at x 4 at = 32 steps, seamless a-walk).
    float pR[4], pI[4], r8R, r8I;
    #pragma unroll
    for (int r = 0; r < 4; ++r) {
        float sn, cs;
        __sincosf(s * (float)(r + 4 * hi - 128), &sn, &cs);
        pR[r] = cs; pI[r] = -sn;
    }
    { float sn, cs; __sincosf(8.f * s, &sn, &cs); r8R = cs; r8I = -sn; }

    // Stage 2 of the 8 per-thread chunks of 64-row a-tile `at` into half.
    // Tile = 4096 x 16B chunks: L = plane*2048 + row*32 + slot.
    // Linear LDS dest (wave base + lane*16); source chunk pre-swizzled
    // (slot = chunk ^ (row&7), rule #21).
    auto stage2 = [&](int at, int half, int ph) {
        #pragma unroll
        for (int u = 0; u < 2; ++u) {
            int it  = ph * 2 + u;              // 0..7
            int L   = it * 512 + tid;          // [0,4096)
            int row = (L >> 5) & 63;
            int cb  = (L & 31) ^ (row & 7);
            const short* g = ((L >> 11) ? Si : Sr) + (at * 64 + row) * 256 + cb * 8;
            __builtin_amdgcn_global_load_lds(
                (glb_uint*)g,
                (lds_uint*)(lds + half * 65536 + (it * 512 + (tid & ~63)) * 16),
                16, 0, 0);
        }
    };

    // Prologue: stage tile 0 fully into half 0.
    #pragma unroll
    for (int ph = 0; ph < 4; ++ph) stage2(0, 0, ph);

    float yr = 0.f, yi = 0.f;
    const int rowoff = col * 512;
    const int swz    = col & 7;

    for (int at = 0; at < 4; ++at) {
        const int cur = at & 1;
        // Drain own stage writes; barrier -> all waves' writes to buf[cur]
        // visible. (Writes to buf[cur^1] may remain in flight: none exist
        // here — stage(at+1) is issued below, after this point.)
        asm volatile("s_waitcnt vmcnt(0)" ::: "memory");
        __builtin_amdgcn_s_barrier();

        const char* buf = lds + cur * 65536;
        f32x16 P[2][4];
        #pragma unroll
        for (int rs = 0; rs < 2; ++rs)
            #pragma unroll
            for (int p = 0; p < 4; ++p) P[rs][p] = {0.f};

        #pragma unroll
        for (int ph = 0; ph < 4; ++ph) {
            // B fragments for this phase's 4 K-steps (L2-resident table).
            short8 Brf[4], Bif[4];
            if constexpr (USE_TABLE) {
                #pragma unroll
                for (int u = 0; u < 4; ++u) {
                    const int ks = ph * 4 + u;
                    Brf[u] = *(const short8*)(tb + ks * 512);
                    Bif[u] = *(const short8*)(tb + 8192 + ks * 512);
                }
            } else {
                #pragma unroll
                for (int u = 0; u < 4; ++u) {
                    #pragma unroll
                    for (int j = 0; j < 8; ++j) {
                        float xb = (float)((ph * 4 + u) * 16 + hi * 8 + j - 128);
                        float sn, cs;
                        __sincosf(t * xb, &sn, &cs);
                        Brf[u][j] = f2bf(cs);
                        Bif[u][j] = f2bf(-sn);
                    }
                }
            }
            // Issue next-tile staging into the OTHER buffer (no wait).
            if (at < 3) stage2(at + 1, cur ^ 1, ph);

            // A fragments: 4 ks x 2 planes x 2 row-subtiles = 16 ds_read_b128.
            short8 Ar[2][4], Ai[2][4];
            #pragma unroll
            for (int rs = 0; rs < 2; ++rs) {
                #pragma unroll
                for (int u = 0; u < 4; ++u) {
                    const int ks = ph * 4 + u;
                    int slot = ((ks * 2 + hi) ^ swz) << 4;
                    Ar[rs][u] = *(const short8*)(buf + rs * 16384 + rowoff + slot);
                    Ai[rs][u] = *(const short8*)(buf + 32768 + rs * 16384 + rowoff + slot);
                }
            }
            // Align waves, then a pure-MFMA cluster (32 MFMAs, 8 indep chains;
            // compiler inserts fine-grained lgkmcnt for the ds_read deps).
            __builtin_amdgcn_s_barrier();
            __builtin_amdgcn_s_setprio(1);
            #pragma unroll
            for (int u = 0; u < 4; ++u) {
                #pragma unroll
                for (int rs = 0; rs < 2; ++rs) {
                    P[rs][0] = __builtin_amdgcn_mfma_f32_32x32x16_bf16(Ar[rs][u], Brf[u], P[rs][0], 0, 0, 0);
                    P[rs][1] = __builtin_amdgcn_mfma_f32_32x32x16_bf16(Ai[rs][u], Bif[u], P[rs][1], 0, 0, 0);
                    P[rs][2] = __builtin_amdgcn_mfma_f32_32x32x16_bf16(Ar[rs][u], Bif[u], P[rs][2], 0, 0, 0);
                    P[rs][3] = __builtin_amdgcn_mfma_f32_32x32x16_bf16(Ai[rs][u], Brf[u], P[rs][3], 0, 0, 0);
                }
            }
            __builtin_amdgcn_s_setprio(0);
        }

        // Epilogue: D col = lane&31 (k), row-in-subtile = (reg&3)+8*(reg>>2)
        // +4*hi; global a = at*64 + rs*32 + q*8 + r + 4*hi - 128 — matches
        // the continuous phasor walk (step = at*8 + rs*4 + q).
        #pragma unroll
        for (int rs = 0; rs < 2; ++rs) {
            #pragma unroll
            for (int q = 0; q < 4; ++q) {
                #pragma unroll
                for (int r = 0; r < 4; ++r) {
                    int reg = q * 4 + r;
                    float Tr = P[rs][0][reg] - P[rs][1][reg];
                    float Ti = P[rs][2][reg] + P[rs][3][reg];
                    yr += pR[r] * Tr - pI[r] * Ti;
                    yi += pR[r] * Ti + pI[r] * Tr;
                }
                #pragma unroll
                for (int r = 0; r < 4; ++r) {   // p[r] *= exp(-i*8s)
                    float nR = pR[r] * r8R - pI[r] * r8I;
                    float nI = pR[r] * r8I + pI[r] * r8R;
                    pR[r] = nR; pI[r] = nI;
                }
            }
        }
    }

    // Lanes l and l+32 hold disjoint a-rows of the same k-col.
    yr += __shfl_xor(yr, 32);
    yi += __shfl_xor(yi, 32);

    if (hi == 0) {
        float wk = w[k];
        out[((size_t)c * MTOT + k) * 2 + 0] = yr * wk;
        out[((size_t)c * MTOT + k) * 2 + 1] = yi * wk;
    }
}

extern "C" void kernel_launch(void* const* d_in, const int* in_sizes, int n_in,
                              void* d_out, int out_size, void* d_ws, size_t ws_size,
                              hipStream_t stream) {
    const float* X      = (const float*)d_in[0];
    const float* angles = (const float*)d_in[1];
    const float* C      = (const float*)d_in[2];
    const float* w      = (const float*)d_in[3];
    float* out = (float*)d_out;

    short* Sr  = (short*)d_ws;           // 1 MB
    short* Si  = Sr + NC * 65536;        // 1 MB
    short* EbT = Si + NC * 65536;        // 17.8 MB (fragment-order Eb table)

    size_t need = ((size_t)NC * 65536 * 2 + (size_t)MTOT * 512) * sizeof(short);
    const bool use_table = ws_size >= need;

    const int LDS_BYTES = 131072;
    dim3 grid(576);                      // 72 ktg-slots x 8 coils; XCD = ktg%8
    if (use_table) {
        (void)hipFuncSetAttribute((const void*)nufft_fwd<1>,
                                  hipFuncAttributeMaxDynamicSharedMemorySize,
                                  LDS_BYTES);
        prep<<<dim3(2048 + MTOT * 32 / 256), dim3(256), 0, stream>>>(
            X, C, angles, Sr, Si, EbT);
        nufft_fwd<1><<<grid, dim3(512), LDS_BYTES, stream>>>(
            angles, w, Sr, Si, EbT, out);
    } else {
        (void)hipFuncSetAttribute((const void*)nufft_fwd<0>,
                                  hipFuncAttributeMaxDynamicSharedMemorySize,
                                  LDS_BYTES);
        prep<<<dim3(2048), dim3(256), 0, stream>>>(X, C, angles, Sr, Si, EbT);
        nufft_fwd<0><<<grid, dim3(512), LDS_BYTES, stream>>>(
            angles, w, Sr, Si, nullptr, out);
    }
}

// Round 9
// 130.125 us; speedup vs baseline: 1.9276x; 1.9276x over previous
//
#include <hip/hip_runtime.h>

#define NC   8
#define MTOT 17408   // NSPOKE*NVEC = 34*512

typedef __attribute__((ext_vector_type(8)))  short short8;
typedef __attribute__((ext_vector_type(16))) float f32x16;

typedef __attribute__((address_space(3))) unsigned       lds_uint;
typedef const __attribute__((address_space(1))) unsigned glb_uint;

static __device__ __forceinline__ short f2bf(float f) {
    union { float f; unsigned u; } v; v.f = f;
    return (short)((v.u + 0x7fffu + ((v.u >> 16) & 1u)) >> 16);
}

// Fused prep (R6-proven). Blocks [0,2048): src[c][a][b] = X*C -> Sr, Si.
// Blocks [2048,4224): Eb table in 32x32x16 B-fragment order:
//   Br[kt][ks] at EbT[(kt*32+ks)*512 + lane*8 + j], Bi at +8192 within kt blk:
//   exp(-i*t_k*b'), k = kt*32+(lane&31), b' = ks*16+(lane>>5)*8+j-128.
__global__ __launch_bounds__(256) void prep(
        const float* __restrict__ X, const float* __restrict__ C,
        const float* __restrict__ angles,
        short* __restrict__ Sr, short* __restrict__ Si,
        short* __restrict__ EbT) {
    int bx = blockIdx.x;
    if (bx < 2048) {
        int idx = bx * 256 + threadIdx.x;   // [0, 8*65536)
        int ab = idx & 65535;
        float xr = X[ab * 2 + 0], xi = X[ab * 2 + 1];
        float cr = C[idx * 2 + 0], ci = C[idx * 2 + 1];
        Sr[idx] = f2bf(xr * cr - xi * ci);
        Si[idx] = f2bf(xr * ci + xi * cr);
    } else {
        int gid  = (bx - 2048) * 256 + threadIdx.x;  // [0, 544*1024)
        int kt   = gid >> 10;
        int r    = gid & 1023;
        int ks   = r >> 6;
        int lane = r & 63;
        int k    = kt * 32 + (lane & 31);
        float t  = angles[k * 2 + 1];
        short8 re, im;
        #pragma unroll
        for (int j = 0; j < 8; ++j) {
            float xb = (float)(ks * 16 + (lane >> 5) * 8 + j - 128);
            float sn, cs;
            __sincosf(t * xb, &sn, &cs);
            re[j] = f2bf(cs);
            im[j] = f2bf(-sn);
        }
        short* base = EbT + (size_t)(kt * 32 + ks) * 512 + lane * 8;
        *(short8*)(base)        = re;
        *(short8*)(base + 8192) = im;
    }
}

// Main: y[c,k] = w[k] * sum_a Ea[k,a] * sum_b src[c,a,b] * Eb[k,b]
// 512 threads = 8 waves = 2 kt (ktloc = wv>>2) x 4-way b-split (ww = wv&3).
// Wave owns kt = ktq*2+ktloc, b in [ww*64, ww*64+64) -> B = 32 VGPR loaded
// ONCE from LDS; acc = 64 AGPR. Eb slice (2 kt, 64KB) staged to LDS once;
// A-tile (32 rows x 256 b x 2 planes = 32KB) double-buffered (128KB total,
// 1 block/CU). One vmcnt(0)+barrier per at-iter (stage issued a full iter
// earlier). b-partials merged at the end via 2KB LDS reduce.
// Grid (272,8): XCD = ktq%8 (272%8==0) -> the 8 coil-blocks of a ktq share
// src planes + Eb slice in one XCD's L2.
template<int USE_TABLE>
__global__ __launch_bounds__(512, 1) void nufft_fwd(
        const float* __restrict__ angles, const float* __restrict__ w,
        const short* __restrict__ SrP, const short* __restrict__ SiP,
        const short* __restrict__ EbT, float* __restrict__ out) {
    extern __shared__ char lds[];   // 131072: Eb [0,64K), A dbuf [64K,128K)

    const int tid   = threadIdx.x;
    const int lane  = tid & 63;
    const int wv    = tid >> 6;         // 0..7
    const int ktloc = wv >> 2;          // 0..1
    const int ww    = wv & 3;           // b-quarter
    const int c     = blockIdx.y;       // coil
    const int ktq   = blockIdx.x;       // 0..271
    const int col   = lane & 31;        // MFMA: A-row / B-col / D-col
    const int hi    = lane >> 5;        // MFMA: K-half selector
    const int kt    = ktq * 2 + ktloc;
    const int k     = kt * 32 + col;
    const float s   = angles[k * 2 + 0];

    const short* Sr = SrP + c * 65536;
    const short* Si = SiP + c * 65536;

    // Phasors p[r] = exp(-i*s*(r+4*hi-128)); rotate by exp(-i*8s) per quad.
    float pR[4], pI[4], r8R, r8I;
    #pragma unroll
    for (int r = 0; r < 4; ++r) {
        float sn, cs;
        __sincosf(s * (float)(r + 4 * hi - 128), &sn, &cs);
        pR[r] = cs; pI[r] = -sn;
    }
    { float sn, cs; __sincosf(8.f * s, &sn, &cs); r8R = cs; r8I = -sn; }

    // Stage A-tile `at` (2048 x 16B chunks; 4/thread) into dbuf half.
    // Linear LDS dest; source chunk pre-swizzled (slot = cb^(row&7), rule 21).
    auto stageA = [&](int at, int half) {
        #pragma unroll
        for (int it = 0; it < 4; ++it) {
            int L   = it * 512 + tid;          // [0,2048)
            int row = (L >> 5) & 31;
            int cb  = (L & 31) ^ (row & 7);
            const short* g = ((L >> 10) ? Si : Sr) + (at * 32 + row) * 256 + cb * 8;
            __builtin_amdgcn_global_load_lds(
                (glb_uint*)g,
                (lds_uint*)(lds + 65536 + half * 32768 + (it * 512 + (tid & ~63)) * 16),
                16, 0, 0);
        }
    };

    // Prologue: stage Eb slice (4096 chunks, linear both sides) + A tile 0.
    if constexpr (USE_TABLE) {
        #pragma unroll
        for (int it = 0; it < 8; ++it) {
            int L = it * 512 + tid;            // [0,4096)
            const short* g = EbT + (size_t)ktq * 32768 + L * 8;
            __builtin_amdgcn_global_load_lds(
                (glb_uint*)g,
                (lds_uint*)(lds + (it * 512 + (tid & ~63)) * 16),
                16, 0, 0);
        }
    }
    stageA(0, 0);

    asm volatile("s_waitcnt vmcnt(0)" ::: "memory");
    __builtin_amdgcn_s_barrier();

    // B fragments for this wave's b-quarter: ks = ww*4+u. 32 VGPR, held.
    short8 Br[4], Bi[4];
    if constexpr (USE_TABLE) {
        const char* eb = lds + ktloc * 32768;
        #pragma unroll
        for (int u = 0; u < 4; ++u) {
            int ks = ww * 4 + u;
            Br[u] = *(const short8*)(eb + ks * 1024 + lane * 16);
            Bi[u] = *(const short8*)(eb + 16384 + ks * 1024 + lane * 16);
        }
    } else {
        const float t = angles[k * 2 + 1];
        #pragma unroll
        for (int u = 0; u < 4; ++u) {
            #pragma unroll
            for (int j = 0; j < 8; ++j) {
                float xb = (float)((ww * 4 + u) * 16 + hi * 8 + j - 128);
                float sn, cs;
                __sincosf(t * xb, &sn, &cs);
                Br[u][j] = f2bf(cs);
                Bi[u][j] = f2bf(-sn);
            }
        }
    }

    float yr = 0.f, yi = 0.f;
    const int rowoff = col * 512;
    const int swz    = col & 7;
    const char* Abase = lds + 65536;

    for (int at = 0; at < 8; ++at) {
        const int cur = at & 1;
        if (at) {   // at==0 synced by prologue barrier
            asm volatile("s_waitcnt vmcnt(0)" ::: "memory");
            __builtin_amdgcn_s_barrier();
        }
        if (at < 7) stageA(at + 1, cur ^ 1);

        // A fragments for this wave's 4 ks (2 planes) from buf[cur].
        const char* buf = Abase + cur * 32768;
        short8 Ar[4], Ai[4];
        #pragma unroll
        for (int u = 0; u < 4; ++u) {
            int ks   = ww * 4 + u;
            int slot = ((ks * 2 + hi) ^ swz) << 4;
            Ar[u] = *(const short8*)(buf + rowoff + slot);
            Ai[u] = *(const short8*)(buf + 16384 + rowoff + slot);
        }

        f32x16 P0 = {0.f}, P1 = {0.f}, P2 = {0.f}, P3 = {0.f};
        __builtin_amdgcn_s_setprio(1);
        #pragma unroll
        for (int u = 0; u < 4; ++u) {
            P0 = __builtin_amdgcn_mfma_f32_32x32x16_bf16(Ar[u], Br[u], P0, 0, 0, 0);
            P1 = __builtin_amdgcn_mfma_f32_32x32x16_bf16(Ai[u], Bi[u], P1, 0, 0, 0);
            P2 = __builtin_amdgcn_mfma_f32_32x32x16_bf16(Ar[u], Bi[u], P2, 0, 0, 0);
            P3 = __builtin_amdgcn_mfma_f32_32x32x16_bf16(Ai[u], Br[u], P3, 0, 0, 0);
        }
        __builtin_amdgcn_s_setprio(0);

        // Epilogue: D col = lane&31 (k), a = at*32 + q*8 + r + 4*hi - 128.
        #pragma unroll
        for (int q = 0; q < 4; ++q) {
            #pragma unroll
            for (int r = 0; r < 4; ++r) {
                int reg = q * 4 + r;
                float Tr = P0[reg] - P1[reg];
                float Ti = P2[reg] + P3[reg];
                yr += pR[r] * Tr - pI[r] * Ti;
                yi += pR[r] * Ti + pI[r] * Tr;
            }
            #pragma unroll
            for (int r = 0; r < 4; ++r) {   // p[r] *= exp(-i*8s)
                float nR = pR[r] * r8R - pI[r] * r8I;
                float nI = pR[r] * r8I + pI[r] * r8R;
                pR[r] = nR; pI[r] = nI;
            }
        }
    }

    // hi-halves hold disjoint a-rows of the same k-col.
    yr += __shfl_xor(yr, 32);
    yi += __shfl_xor(yi, 32);

    // Merge the 4 b-quarter partials per kt via LDS (reuse Eb area).
    __syncthreads();
    if (hi == 0) {
        *(float*)(lds + ((wv * 32 + col) * 8) + 0) = yr;
        *(float*)(lds + ((wv * 32 + col) * 8) + 4) = yi;
    }
    __syncthreads();
    if (ww == 0 && hi == 0) {
        float sr = 0.f, si = 0.f;
        #pragma unroll
        for (int j = 0; j < 4; ++j) {
            sr += *(const float*)(lds + (((ktloc * 4 + j) * 32 + col) * 8) + 0);
            si += *(const float*)(lds + (((ktloc * 4 + j) * 32 + col) * 8) + 4);
        }
        float wk = w[k];
        out[((size_t)c * MTOT + k) * 2 + 0] = sr * wk;
        out[((size_t)c * MTOT + k) * 2 + 1] = si * wk;
    }
}

extern "C" void kernel_launch(void* const* d_in, const int* in_sizes, int n_in,
                              void* d_out, int out_size, void* d_ws, size_t ws_size,
                              hipStream_t stream) {
    const float* X      = (const float*)d_in[0];
    const float* angles = (const float*)d_in[1];
    const float* C      = (const float*)d_in[2];
    const float* w      = (const float*)d_in[3];
    float* out = (float*)d_out;

    short* Sr  = (short*)d_ws;           // 1 MB
    short* Si  = Sr + NC * 65536;        // 1 MB
    short* EbT = Si + NC * 65536;        // 17.8 MB (fragment-order Eb table)

    size_t need = ((size_t)NC * 65536 * 2 + (size_t)MTOT * 512) * sizeof(short);
    const bool use_table = ws_size >= need;

    const int LDS_BYTES = 131072;
    dim3 grid(MTOT / 64, NC);            // (272, 8); XCD = ktq%8
    if (use_table) {
        (void)hipFuncSetAttribute((const void*)nufft_fwd<1>,
                                  hipFuncAttributeMaxDynamicSharedMemorySize,
                                  LDS_BYTES);
        prep<<<dim3(2048 + MTOT * 32 / 256), dim3(256), 0, stream>>>(
            X, C, angles, Sr, Si, EbT);
        nufft_fwd<1><<<grid, dim3(512), LDS_BYTES, stream>>>(
            angles, w, Sr, Si, EbT, out);
    } else {
        (void)hipFuncSetAttribute((const void*)nufft_fwd<0>,
                                  hipFuncAttributeMaxDynamicSharedMemorySize,
                                  LDS_BYTES);
        prep<<<dim3(2048), dim3(256), 0, stream>>>(X, C, angles, Sr, Si, EbT);
        nufft_fwd<0><<<grid, dim3(512), LDS_BYTES, stream>>>(
            angles, w, Sr, Si, nullptr, out);
    }
}